// Round 1
// 329.146 us; speedup vs baseline: 1.0698x; 1.0698x over previous
//
#include <hip/hip_runtime.h>

#define N_ 4096
#define DIM_ 512
#define H_ 8
#define DH_ 64
#define M_ 266
#define MP_ 272      // ksum/qp live range padded to 272 (17 tiles of 16)
#define MP2_ 288     // out-GEMM K padded to 9 chunks of 32
#define MP3_ 320     // ksuma / projp m padded to 5 chunks of 64
#define SLABM_ 280   // ctx partial-slab m extent (>= M_=266, trimmed to fit overlay)
#define NZ_ 8        // n-split for ctxfused
#define NT_ 16384
#define BH_ 32

#define NORMC 0.3535533905932738f   // 64^-0.25
#define RATIOC 0.06131393394849658f // 266^-0.5
#define EPSK 1e-4f
#define DIAGC 0.0625f               // 0.5 * normalizer^2

// ---- ws layout (byte offsets), total ~71.0 MB ----
// ctx slabs (18,350,080 B) overlay xbf+wqb+wkb+wvb, dead after qkv_mfma.
#define PROJP_B 0ul            // 40960
#define KMAX_B  40960ul        // 128
#define KSUMA_B 41088ul        // 40960
#define WO_B    82048ul        // 524288
#define CTXT_B  606336ul       // 1179648
#define DIAGQ_B 1785984ul      // 262144
#define DIAGK_B 2048128ul      // 262144
#define XBF_B   2310272ul      // 16777216
#define WQ_B    19087488ul     // 524288
#define WK_B    19611776ul     // 524288
#define WV_B    20136064ul     // 524288
#define CTXA_B  2310272ul      // == XBF_B, 32*8*280*64*4 = 18350080 (ends at Q_B)
#define Q_B     20660352ul     // 16777216
#define K_B     37437568ul     // 16777216
#define VT_B    54214784ul     // 16777216 -> end 70991,  total 70,992,000

typedef __bf16 bf16x8 __attribute__((ext_vector_type(8)));
typedef float f32x4 __attribute__((ext_vector_type(4)));
#define MFMA16(a, b, c) __builtin_amdgcn_mfma_f32_16x16x32_bf16((a), (b), (c), 0, 0, 0)

__device__ __forceinline__ float bfu(unsigned short u) {
  union { unsigned int i; float f; } x; x.i = ((unsigned int)u) << 16; return x.f;
}
__device__ __forceinline__ unsigned short f2bf(float f) {
  union { float f; unsigned int i; } u; u.f = f;
  unsigned int r = u.i + 0x7fffu + ((u.i >> 16) & 1u);
  return (unsigned short)(r >> 16);
}
__device__ __forceinline__ void atomicMaxF(float* addr, float val) {
  int* ai = (int*)addr;
  while (true) {
    float cur = __int_as_float(*(volatile int*)ai);
    if (val <= cur) break;
    int old = atomicCAS(ai, __float_as_int(cur), __float_as_int(val));
    if (old == __float_as_int(cur)) break;
  }
}

// ---------------- fp32 -> bf16 conversion ----------------
__global__ void cvt_kernel(const float* __restrict__ src, unsigned short* __restrict__ dst, int n) {
  int i = (blockIdx.x * 256 + threadIdx.x) * 4;
  const int stride = gridDim.x * 1024;
  for (; i < n; i += stride) {
    const float4 v = *(const float4*)(src + i);
    ushort4 u;
    u.x = f2bf(v.x); u.y = f2bf(v.y); u.z = f2bf(v.z); u.w = f2bf(v.w);
    *(ushort4*)(dst + i) = u;
  }
}

// ---------------- setup: proj cvt+pad(320), kmax init, ksuma zero ----------------
__global__ void setup_kernel(const float* __restrict__ proj,
                             unsigned short* __restrict__ projp,
                             float* __restrict__ kmax,
                             float* __restrict__ ksuma) {
  const int i = blockIdx.x * 256 + threadIdx.x;
  const int stride = gridDim.x * 256;
  for (int j = i; j < MP3_ * DH_; j += stride)
    projp[j] = (j < M_ * DH_) ? f2bf(proj[j]) : (unsigned short)0;
  for (int j = i; j < BH_; j += stride) kmax[j] = -3e38f;
  for (int j = i; j < BH_ * MP3_; j += stride) ksuma[j] = 0.f;
}

// ---------------- QKV projection: 128x128 LDS-staged MFMA GEMM ----------------
__global__ __launch_bounds__(256) void qkv_mfma(
    const unsigned short* __restrict__ x, const unsigned short* __restrict__ Wq,
    const unsigned short* __restrict__ Wk, const unsigned short* __restrict__ Wv,
    unsigned short* __restrict__ Q, unsigned short* __restrict__ K,
    unsigned short* __restrict__ VT) {
  __shared__ unsigned short As[128 * 64];
  __shared__ unsigned short Bs[128 * 64];
  const int z = blockIdx.z;
  const unsigned short* W = (z == 0) ? Wq : (z == 1) ? Wk : Wv;
  const int t0 = blockIdx.x * 128, e0 = blockIdx.y * 128;
  const int tid = threadIdx.x;
  const int wv = tid >> 6, lane = tid & 63;
  const int r = lane & 15, q = lane >> 4;
  const int wr = (wv >> 1) * 64, wc = (wv & 1) * 64;
  f32x4 acc[4][4];
#pragma unroll
  for (int i = 0; i < 4; ++i)
#pragma unroll
    for (int j = 0; j < 4; ++j) acc[i][j] = (f32x4){0.f, 0.f, 0.f, 0.f};
  const int srow = tid >> 3, scol = (tid & 7) * 8;
  for (int k0 = 0; k0 < DIM_; k0 += 64) {
#pragma unroll
    for (int j = 0; j < 4; ++j) {
      const int rr = srow + j * 32;
      *(uint4*)&As[rr * 64 + scol] = *(const uint4*)&x[(size_t)(t0 + rr) * DIM_ + k0 + scol];
      *(uint4*)&Bs[rr * 64 + scol] = *(const uint4*)&W[(size_t)(e0 + rr) * DIM_ + k0 + scol];
    }
    __syncthreads();
#pragma unroll
    for (int kc = 0; kc < 2; ++kc) {
      bf16x8 af[4], bfr[4];
#pragma unroll
      for (int rt = 0; rt < 4; ++rt)
        af[rt] = *(const bf16x8*)&As[(wr + rt * 16 + r) * 64 + kc * 32 + q * 8];
#pragma unroll
      for (int ct = 0; ct < 4; ++ct)
        bfr[ct] = *(const bf16x8*)&Bs[(wc + ct * 16 + r) * 64 + kc * 32 + q * 8];
#pragma unroll
      for (int rt = 0; rt < 4; ++rt)
#pragma unroll
        for (int ct = 0; ct < 4; ++ct)
          acc[rt][ct] = MFMA16(af[rt], bfr[ct], acc[rt][ct]);
    }
    __syncthreads();
  }
  if (z < 2) {
    unsigned short* dst = (z == 0) ? Q : K;
#pragma unroll
    for (int rt = 0; rt < 4; ++rt) {
#pragma unroll
      for (int ct = 0; ct < 4; ++ct) {
        const int e = e0 + wc + ct * 16 + r;
#pragma unroll
        for (int i = 0; i < 4; ++i) {
          const int t = t0 + wr + rt * 16 + q * 4 + i;
          dst[(size_t)t * DIM_ + e] = f2bf(acc[rt][ct][i]);
        }
      }
    }
  } else {
#pragma unroll
    for (int rt = 0; rt < 4; ++rt) {
      const int t = t0 + wr + rt * 16 + q * 4;
      const int b_ = t >> 12, n = t & (N_ - 1);
#pragma unroll
      for (int ct = 0; ct < 4; ++ct) {
        const int e = e0 + wc + ct * 16 + r;
        const int h = e >> 6, dh = e & 63;
        ushort4 pk;
        pk.x = f2bf(acc[rt][ct][0]); pk.y = f2bf(acc[rt][ct][1]);
        pk.z = f2bf(acc[rt][ct][2]); pk.w = f2bf(acc[rt][ct][3]);
        *(ushort4*)&VT[((size_t)((b_ * H_ + h) * DH_ + dh)) * N_ + n] = pk;
      }
    }
  }
}

// ---------------- diag: DIAGC * sum(t*t) per (bh, n), stored bf16 ----------------
__global__ void diag_kernel(const unsigned short* __restrict__ Q,
                            const unsigned short* __restrict__ K,
                            unsigned short* __restrict__ dq, unsigned short* __restrict__ dk) {
  const int i = blockIdx.x * 256 + threadIdx.x;
  const int bh = i >> 12, n = i & (N_ - 1);
  const int b_ = bh >> 3, h = bh & 7;
  const unsigned short* src = ((blockIdx.y == 0) ? Q : K) + (size_t)(b_ * N_ + n) * DIM_ + h * DH_;
  float s = 0.f;
#pragma unroll
  for (int c = 0; c < 16; ++c) {
    const ushort4 u = ((const ushort4*)src)[c];
    const float a = bfu(u.x), b2 = bfu(u.y), cc = bfu(u.z), d = bfu(u.w);
    s += a * a + b2 * b2 + cc * cc + d * d;
  }
  ((blockIdx.y == 0) ? dq : dk)[i] = f2bf(s * DIAGC);
}

// ---------------- kmax (MFMA): 2 n-strips per wave, 68 MFMAs/wave ----------------
__global__ __launch_bounds__(256) void kmax_mfma(
    const unsigned short* __restrict__ K, const unsigned short* __restrict__ projp,
    float* __restrict__ kmax) {
  const int bh = blockIdx.x, n0 = blockIdx.y * 128;
  const int wv = threadIdx.x >> 6, lane = threadIdx.x & 63;
  const int r = lane & 15, q = lane >> 4;
  const int b_ = bh >> 3, h = bh & 7;
  bf16x8 kb[2][2];
#pragma unroll
  for (int nt = 0; nt < 2; ++nt) {
    const int n = n0 + wv * 32 + nt * 16 + r;
    const unsigned short* krow = K + (size_t)(b_ * N_ + n) * DIM_ + h * DH_;
    kb[nt][0] = *(const bf16x8*)(krow + q * 8);
    kb[nt][1] = *(const bf16x8*)(krow + 32 + q * 8);
  }
  float runmax = -3e38f;
  for (int mt = 0; mt < 17; ++mt) {
    const unsigned short* prow = projp + (size_t)(mt * 16 + r) * DH_;
    const bf16x8 a0 = *(const bf16x8*)(prow + q * 8);
    const bf16x8 a1 = *(const bf16x8*)(prow + 32 + q * 8);
#pragma unroll
    for (int nt = 0; nt < 2; ++nt) {
      f32x4 acc = (f32x4){0.f, 0.f, 0.f, 0.f};
      acc = MFMA16(a0, kb[nt][0], acc);
      acc = MFMA16(a1, kb[nt][1], acc);
#pragma unroll
      for (int i = 0; i < 4; ++i) {
        const int m = mt * 16 + q * 4 + i;
        if (m < M_) runmax = fmaxf(runmax, acc[i]);
      }
    }
  }
  for (int s2 = 1; s2 < 64; s2 <<= 1) runmax = fmaxf(runmax, __shfl_xor(runmax, s2, 64));
  __shared__ float wm[4];
  if (lane == 0) wm[wv] = runmax;
  __syncthreads();
  if (threadIdx.x == 0) {
    const float m = fmaxf(fmaxf(wm[0], wm[1]), fmaxf(wm[2], wm[3])) * NORMC;
    atomicMaxF(&kmax[bh], m);
  }
}

// ---------------- fused: td -> exp -> kp; ctx += kp x VT; ksum ----------------
// z-split NZ_=8 (512 n per block, 8 chunks of 64); ctx partials stored to
// per-z slabs with transposed coalesced layout slab[bh][z][m][d] (plain stores,
// no atomics); reduced + transposed back in pack_kernel.
__global__ __launch_bounds__(256) void ctxfused_mfma(
    const unsigned short* __restrict__ K, const unsigned short* __restrict__ VT,
    const unsigned short* __restrict__ projp, const unsigned short* __restrict__ diag_k,
    const float* __restrict__ kmaxv, float* __restrict__ ksuma,
    float* __restrict__ slab) {
  __shared__ unsigned short kll[64][72];
  __shared__ unsigned short vtl[64][72];
  __shared__ unsigned short kpl[64][72];
  __shared__ float dgl[64];
  const int bh = blockIdx.x, m0 = blockIdx.y * 64, zi = blockIdx.z;
  const int nbase = zi * 512;
  const int tid = threadIdx.x;
  const int wv = tid >> 6, lane = tid & 63;
  const int r = lane & 15, q = lane >> 4;
  const int b_ = bh >> 3, h = bh & 7;
  const float km = kmaxv[bh];
  const unsigned short* prow = projp + (size_t)(m0 + wv * 16 + r) * DH_;
  const bf16x8 p0 = *(const bf16x8*)(prow + q * 8);
  const bf16x8 p1 = *(const bf16x8*)(prow + 32 + q * 8);
  const unsigned short* kbase = K + (size_t)(b_ * N_) * DIM_ + h * DH_;
  const unsigned short* vbase = VT + (size_t)bh * DH_ * N_;
  f32x4 cacc[4];
#pragma unroll
  for (int i = 0; i < 4; ++i) cacc[i] = (f32x4){0.f, 0.f, 0.f, 0.f};
  float ksa[4] = {0.f, 0.f, 0.f, 0.f};
  for (int nc = 0; nc < 8; ++nc) {
    const int n0c = nbase + nc * 64;
#pragma unroll
    for (int j = 0; j < 4; ++j) {
      const int idx = tid + j * 256;
      const int rr = idx >> 4, c4 = (idx & 15) << 2;
      *(ushort4*)&kll[rr][c4] = *(const ushort4*)&kbase[(size_t)(n0c + rr) * DIM_ + c4];
      *(ushort4*)&vtl[rr][c4] = *(const ushort4*)&vbase[(size_t)rr * N_ + n0c + c4];
    }
    if (tid < 16) {
      const ushort4 du = *(const ushort4*)&diag_k[bh * N_ + n0c + tid * 4];
      dgl[tid * 4 + 0] = bfu(du.x); dgl[tid * 4 + 1] = bfu(du.y);
      dgl[tid * 4 + 2] = bfu(du.z); dgl[tid * 4 + 3] = bfu(du.w);
    }
    __syncthreads();
#pragma unroll
    for (int nt = 0; nt < 4; ++nt) {
      const bf16x8 kb0 = *(const bf16x8*)&kll[nt * 16 + r][q * 8];
      const bf16x8 kb1 = *(const bf16x8*)&kll[nt * 16 + r][32 + q * 8];
      f32x4 acc = (f32x4){0.f, 0.f, 0.f, 0.f};
      acc = MFMA16(p0, kb0, acc);
      acc = MFMA16(p1, kb1, acc);
      const float dgk = dgl[nt * 16 + r];
#pragma unroll
      for (int i = 0; i < 4; ++i) {
        const int m = m0 + wv * 16 + q * 4 + i;
        float kp = 0.f;
        if (m < M_) {
          const float arg = fminf(NORMC * acc[i] - dgk - km, 0.f);
          kp = RATIOC * (__expf(arg) + EPSK);
        }
        kpl[wv * 16 + q * 4 + i][nt * 16 + r] = f2bf(kp);
        ksa[i] += kp;
      }
    }
    __syncthreads();
    {
      const bf16x8 a0 = *(const bf16x8*)&kpl[wv * 16 + r][q * 8];
      const bf16x8 a1 = *(const bf16x8*)&kpl[wv * 16 + r][32 + q * 8];
#pragma unroll
      for (int ct = 0; ct < 4; ++ct) {
        const bf16x8 b0 = *(const bf16x8*)&vtl[ct * 16 + r][q * 8];
        const bf16x8 b1 = *(const bf16x8*)&vtl[ct * 16 + r][32 + q * 8];
        cacc[ct] = MFMA16(a0, b0, cacc[ct]);
        cacc[ct] = MFMA16(a1, b1, cacc[ct]);
      }
    }
    __syncthreads();
  }
#pragma unroll
  for (int i = 0; i < 4; ++i)
    for (int s2 = 1; s2 < 16; s2 <<= 1) ksa[i] += __shfl_xor(ksa[i], s2, 64);
  if (r == 0) {
#pragma unroll
    for (int i = 0; i < 4; ++i)
      atomicAdd(&ksuma[bh * MP3_ + m0 + wv * 16 + q * 4 + i], ksa[i]);
  }
  // coalesced partial-slab store: slab[bh][z][m][d]; lanes r -> contiguous 64B lines
  float* sl = slab + (size_t)(bh * NZ_ + zi) * SLABM_ * DH_;
#pragma unroll
  for (int ct = 0; ct < 4; ++ct) {
#pragma unroll
    for (int i = 0; i < 4; ++i) {
      const int m = m0 + wv * 16 + q * 4 + i;
      if (m < SLABM_) sl[(size_t)m * DH_ + ct * 16 + r] = cacc[ct][i];
    }
  }
}

// ---------------- pack: reduce 8 z-slabs [m][d] fp32 -> transpose -> ctxT [d][288] bf16 ----
__global__ __launch_bounds__(256) void pack_kernel(const float* __restrict__ slab,
                                                   unsigned short* __restrict__ ctxT) {
  __shared__ float t[64][65];
  const int bh = blockIdx.x, m0 = blockIdx.y * 64;
  const int tid = threadIdx.x;
  const int mr = tid >> 4, d4 = (tid & 15) * 4;
#pragma unroll
  for (int pass = 0; pass < 4; ++pass) {
    const int ml = pass * 16 + mr;
    const int m = m0 + ml;
    float4 s = {0.f, 0.f, 0.f, 0.f};
    if (m < SLABM_) {
#pragma unroll
      for (int z = 0; z < NZ_; ++z) {
        const float4 v =
            *(const float4*)&slab[((size_t)(bh * NZ_ + z) * SLABM_ + m) * DH_ + d4];
        s.x += v.x; s.y += v.y; s.z += v.z; s.w += v.w;
      }
    }
    t[ml][d4 + 0] = s.x; t[ml][d4 + 1] = s.y; t[ml][d4 + 2] = s.z; t[ml][d4 + 3] = s.w;
  }
  __syncthreads();
  const int mc = tid & 63, dbase = tid >> 6;
  const int mo = m0 + mc;
  if (mo < MP2_) {
#pragma unroll
    for (int j = 0; j < 16; ++j) {
      const int d = dbase + j * 4;
      ctxT[((size_t)bh * DH_ + d) * MP2_ + mo] = f2bf(t[mc][d]);
    }
  }
}

// ---------------- fused QP + out GEMM (2 barriers, register dinv) ----------------
__global__ __launch_bounds__(256) void qpout_mfma(
    const unsigned short* __restrict__ Qb, const unsigned short* __restrict__ projp,
    const unsigned short* __restrict__ diag_q, const float* __restrict__ ksuma,
    const unsigned short* __restrict__ ctxT, unsigned short* __restrict__ attn) {
  __shared__ unsigned short qps[64][296];
  __shared__ float ksums[MP_];
  const int bh = blockIdx.x, n0 = blockIdx.y * 64;
  const int wv = threadIdx.x >> 6, lane = threadIdx.x & 63;
  const int r = lane & 15, q = lane >> 4;
  const int b_ = bh >> 3, h = bh & 7;
  for (int i = threadIdx.x; i < MP_; i += 256) ksums[i] = ksuma[bh * MP3_ + i];
  {  // zero pad cols 272..295 (phase C reads through col 287)
    const int row = threadIdx.x & 63, c0 = MP_ + (threadIdx.x >> 6) * 6;
#pragma unroll
    for (int j = 0; j < 6; ++j) qps[row][c0 + j] = 0;
  }
  __syncthreads();
  // Phase A: QP GEMM; A = Q rows (n), B = proj rows (m)
  const int nrow = n0 + wv * 16 + r;
  const unsigned short* qrow = Qb + (size_t)(b_ * N_ + nrow) * DIM_ + h * DH_;
  const bf16x8 a0 = *(const bf16x8*)(qrow + q * 8);
  const bf16x8 a1 = *(const bf16x8*)(qrow + 32 + q * 8);
  float tdv[17][4];
  for (int mt = 0; mt < 17; ++mt) {
    const unsigned short* prow = projp + (size_t)(mt * 16 + r) * DH_;
    const bf16x8 p0 = *(const bf16x8*)(prow + q * 8);
    const bf16x8 p1 = *(const bf16x8*)(prow + 32 + q * 8);
    f32x4 acc = (f32x4){0.f, 0.f, 0.f, 0.f};
    acc = MFMA16(a0, p0, acc);
    acc = MFMA16(a1, p1, acc);
#pragma unroll
    for (int i = 0; i < 4; ++i) tdv[mt][i] = NORMC * acc[i];
  }
  // per-row max over m (lane covers m = mt*16 + r -> butterfly over r bits)
  float rmax[4];
#pragma unroll
  for (int i = 0; i < 4; ++i) {
    float v = -3e38f;
    for (int mt = 0; mt < 17; ++mt) {
      const int m = mt * 16 + r;
      if (m < M_) v = fmaxf(v, tdv[mt][i]);
    }
    rmax[i] = v;
  }
  for (int s2 = 1; s2 < 16; s2 <<= 1)
#pragma unroll
    for (int i = 0; i < 4; ++i) rmax[i] = fmaxf(rmax[i], __shfl_xor(rmax[i], s2, 64));
  float dgq[4];
#pragma unroll
  for (int i = 0; i < 4; ++i) dgq[i] = bfu(diag_q[bh * N_ + n0 + wv * 16 + q * 4 + i]);
  // exp, write qps, accumulate denominator partials in registers
  float part[4] = {0.f, 0.f, 0.f, 0.f};
  for (int mt = 0; mt < 17; ++mt) {
#pragma unroll
    for (int i = 0; i < 4; ++i) {
      const int m = mt * 16 + r;
      unsigned short qb = 0;
      if (m < M_) {
        const float arg = fminf(tdv[mt][i] - dgq[i] - rmax[i], 0.f);
        qb = f2bf(RATIOC * (__expf(arg) + EPSK));
      }
      qps[wv * 16 + q * 4 + i][m] = qb;
      part[i] += bfu(qb) * ksums[m];
    }
  }
  // butterfly over r bits -> full denominator for rows q*4+i (stays in this lane group)
  for (int s2 = 1; s2 < 16; s2 <<= 1)
#pragma unroll
    for (int i = 0; i < 4; ++i) part[i] += __shfl_xor(part[i], s2, 64);
  float dinv[4];
#pragma unroll
  for (int i = 0; i < 4; ++i) dinv[i] = 1.f / fmaxf(part[i], 1e-30f);
  __syncthreads();
  // Phase C: out = qp . ctxT  (K = 288)
  f32x4 oacc[4];
#pragma unroll
  for (int i = 0; i < 4; ++i) oacc[i] = (f32x4){0.f, 0.f, 0.f, 0.f};
  const unsigned short* cbase = ctxT + (size_t)bh * DH_ * MP2_;
  for (int kc = 0; kc < 9; ++kc) {
    const bf16x8 a = *(const bf16x8*)&qps[wv * 16 + r][kc * 32 + q * 8];
#pragma unroll
    for (int dt = 0; dt < 4; ++dt) {
      const bf16x8 b = *(const bf16x8*)&cbase[(size_t)(dt * 16 + r) * MP2_ + kc * 32 + q * 8];
      oacc[dt] = MFMA16(a, b, oacc[dt]);
    }
  }
#pragma unroll
  for (int dt = 0; dt < 4; ++dt) {
    const int d = dt * 16 + r;
#pragma unroll
    for (int i = 0; i < 4; ++i) {
      const int nn = wv * 16 + q * 4 + i;
      const float o = oacc[dt][i] * dinv[i];
      attn[(size_t)(b_ * N_ + n0 + nn) * DIM_ + h * DH_ + d] = f2bf(o);
    }
  }
}

// ---------------- final: 128x128 LDS-staged MFMA GEMM + residual (fp32 I/O) ----------------
__global__ __launch_bounds__(256) void final_mfma(
    const unsigned short* __restrict__ attn, const unsigned short* __restrict__ Wo,
    const float* __restrict__ bo, const float* __restrict__ x,
    float* __restrict__ out) {
  __shared__ unsigned short As[128 * 64];
  __shared__ unsigned short Bs[128 * 64];
  const int t0 = blockIdx.x * 128, e0 = blockIdx.y * 128;
  const int tid = threadIdx.x;
  const int wv = tid >> 6, lane = tid & 63;
  const int r = lane & 15, q = lane >> 4;
  const int wr = (wv >> 1) * 64, wc = (wv & 1) * 64;
  f32x4 acc[4][4];
#pragma unroll
  for (int i = 0; i < 4; ++i)
#pragma unroll
    for (int j = 0; j < 4; ++j) acc[i][j] = (f32x4){0.f, 0.f, 0.f, 0.f};
  const int srow = tid >> 3, scol = (tid & 7) * 8;
  for (int k0 = 0; k0 < DIM_; k0 += 64) {
#pragma unroll
    for (int j = 0; j < 4; ++j) {
      const int rr = srow + j * 32;
      *(uint4*)&As[rr * 64 + scol] = *(const uint4*)&attn[(size_t)(t0 + rr) * DIM_ + k0 + scol];
      *(uint4*)&Bs[rr * 64 + scol] = *(const uint4*)&Wo[(size_t)(e0 + rr) * DIM_ + k0 + scol];
    }
    __syncthreads();
#pragma unroll
    for (int kc = 0; kc < 2; ++kc) {
      bf16x8 af[4], bfr[4];
#pragma unroll
      for (int rt = 0; rt < 4; ++rt)
        af[rt] = *(const bf16x8*)&As[(wr + rt * 16 + r) * 64 + kc * 32 + q * 8];
#pragma unroll
      for (int ct = 0; ct < 4; ++ct)
        bfr[ct] = *(const bf16x8*)&Bs[(wc + ct * 16 + r) * 64 + kc * 32 + q * 8];
#pragma unroll
      for (int rt = 0; rt < 4; ++rt)
#pragma unroll
        for (int ct = 0; ct < 4; ++ct)
          acc[rt][ct] = MFMA16(af[rt], bfr[ct], acc[rt][ct]);
    }
    __syncthreads();
  }
#pragma unroll
  for (int rt = 0; rt < 4; ++rt) {
#pragma unroll
    for (int ct = 0; ct < 4; ++ct) {
      const int c = e0 + wc + ct * 16 + r;
      const float bov = bo[c];
#pragma unroll
      for (int i = 0; i < 4; ++i) {
        const int t = t0 + wr + rt * 16 + q * 4 + i;
        out[(size_t)t * DIM_ + c] = acc[rt][ct][i] + bov + x[(size_t)t * DIM_ + c];
      }
    }
  }
}

extern "C" void kernel_launch(void* const* d_in, const int* in_sizes, int n_in,
                              void* d_out, int out_size, void* d_ws, size_t ws_size,
                              hipStream_t stream) {
  const float* x = (const float*)d_in[0];
  const float* Wq = (const float*)d_in[1];
  const float* Wk = (const float*)d_in[2];
  const float* Wv = (const float*)d_in[3];
  const float* Wo = (const float*)d_in[4];
  const float* bo = (const float*)d_in[5];
  const float* proj = (const float*)d_in[6];
  char* ws = (char*)d_ws;
  unsigned short* projp = (unsigned short*)(ws + PROJP_B);
  float* kmax = (float*)(ws + KMAX_B);
  float* ksuma = (float*)(ws + KSUMA_B);
  float* ctxa = (float*)(ws + CTXA_B);
  unsigned short* ctxT = (unsigned short*)(ws + CTXT_B);
  unsigned short* diag_q = (unsigned short*)(ws + DIAGQ_B);
  unsigned short* diag_k = (unsigned short*)(ws + DIAGK_B);
  unsigned short* xbf = (unsigned short*)(ws + XBF_B);
  unsigned short* wqb = (unsigned short*)(ws + WQ_B);
  unsigned short* wkb = (unsigned short*)(ws + WK_B);
  unsigned short* wvb = (unsigned short*)(ws + WV_B);
  unsigned short* wob = (unsigned short*)(ws + WO_B);
  unsigned short* Q = (unsigned short*)(ws + Q_B);
  unsigned short* K = (unsigned short*)(ws + K_B);
  unsigned short* VT = (unsigned short*)(ws + VT_B);
  unsigned short* attn = K;  // K dead after ctxfused_mfma
  float* out = (float*)d_out;

  cvt_kernel<<<1024, 256, 0, stream>>>(x, xbf, 8388608);
  cvt_kernel<<<128, 256, 0, stream>>>(Wq, wqb, 262144);
  cvt_kernel<<<128, 256, 0, stream>>>(Wk, wkb, 262144);
  cvt_kernel<<<128, 256, 0, stream>>>(Wv, wvb, 262144);
  cvt_kernel<<<128, 256, 0, stream>>>(Wo, wob, 262144);
  setup_kernel<<<80, 256, 0, stream>>>(proj, projp, kmax, ksuma);
  qkv_mfma<<<dim3(NT_ / 128, DIM_ / 128, 3), 256, 0, stream>>>(xbf, wqb, wkb, wvb, Q, K, VT);
  diag_kernel<<<dim3(512, 2), 256, 0, stream>>>(Q, K, diag_q, diag_k);
  kmax_mfma<<<dim3(BH_, 32), 256, 0, stream>>>(K, projp, kmax);
  ctxfused_mfma<<<dim3(BH_, 5, NZ_), 256, 0, stream>>>(K, VT, projp, diag_k, kmax, ksuma, ctxa);
  pack_kernel<<<dim3(BH_, 5), 256, 0, stream>>>(ctxa, ctxT);
  qpout_mfma<<<dim3(BH_, 64), 256, 0, stream>>>(Q, projp, diag_q, ksuma, ctxT, attn);
  final_mfma<<<dim3(NT_ / 128, DIM_ / 128), 256, 0, stream>>>(attn, wob, bo, x, out);
}

// Round 2
// 326.990 us; speedup vs baseline: 1.0768x; 1.0066x over previous
//
#include <hip/hip_runtime.h>

#define N_ 4096
#define DIM_ 512
#define H_ 8
#define DH_ 64
#define M_ 266
#define MP_ 272      // ksum/qp live range padded to 272 (17 tiles of 16)
#define MP2_ 288     // out-GEMM K padded to 9 chunks of 32
#define MP3_ 320     // ksuma / projp m padded to 5 chunks of 64
#define SLABM_ 280   // ctx partial-slab m extent (>= M_=266, trimmed to fit overlay)
#define NZ_ 8        // n-split for ctxfused
#define NT_ 16384
#define BH_ 32

#define NORMC 0.3535533905932738f   // 64^-0.25
#define RATIOC 0.06131393394849658f // 266^-0.5
#define EPSK 1e-4f
#define DIAGC 0.0625f               // 0.5 * normalizer^2
// folded exp2 constants: qp = exp2(min(raw*KA + Cl, LOG2R)) + REPS
#define KA 0.51006971f              // NORMC * log2(e)
#define LOG2R -4.0276408f           // log2(RATIOC)
#define LOG2E 1.4426950408889634f
#define REPS 6.131393e-6f           // RATIOC * EPSK

// ---- ws layout (byte offsets), total ~71.0 MB ----
// ctx slabs (18,350,080 B) overlay xbf+wqb+wkb+wvb, dead after qkv_mfma.
#define PROJP_B 0ul            // 40960
#define KMAX_B  40960ul        // 128
#define KSUMA_B 41088ul        // 40960
#define WO_B    82048ul        // 524288
#define CTXT_B  606336ul       // 1179648
#define DIAGQ_B 1785984ul      // 262144
#define DIAGK_B 2048128ul      // 262144
#define XBF_B   2310272ul      // 16777216
#define WQ_B    19087488ul     // 524288
#define WK_B    19611776ul     // 524288
#define WV_B    20136064ul     // 524288
#define CTXA_B  2310272ul      // == XBF_B, 32*8*280*64*4 = 18350080 (ends at Q_B)
#define Q_B     20660352ul     // 16777216
#define K_B     37437568ul     // 16777216
#define VT_B    54214784ul     // 16777216

typedef __bf16 bf16x8 __attribute__((ext_vector_type(8)));
typedef float f32x4 __attribute__((ext_vector_type(4)));
#define MFMA16(a, b, c) __builtin_amdgcn_mfma_f32_16x16x32_bf16((a), (b), (c), 0, 0, 0)

__device__ __forceinline__ float bfu(unsigned short u) {
  union { unsigned int i; float f; } x; x.i = ((unsigned int)u) << 16; return x.f;
}
__device__ __forceinline__ unsigned short f2bf(float f) {
  union { float f; unsigned int i; } u; u.f = f;
  unsigned int r = u.i + 0x7fffu + ((u.i >> 16) & 1u);
  return (unsigned short)(r >> 16);
}
__device__ __forceinline__ void atomicMaxF(float* addr, float val) {
  int* ai = (int*)addr;
  while (true) {
    float cur = __int_as_float(*(volatile int*)ai);
    if (val <= cur) break;
    int old = atomicCAS(ai, __float_as_int(cur), __float_as_int(val));
    if (old == __float_as_int(cur)) break;
  }
}

// ---------------- fp32 -> bf16 conversion ----------------
__global__ void cvt_kernel(const float* __restrict__ src, unsigned short* __restrict__ dst, int n) {
  int i = (blockIdx.x * 256 + threadIdx.x) * 4;
  const int stride = gridDim.x * 1024;
  for (; i < n; i += stride) {
    const float4 v = *(const float4*)(src + i);
    ushort4 u;
    u.x = f2bf(v.x); u.y = f2bf(v.y); u.z = f2bf(v.z); u.w = f2bf(v.w);
    *(ushort4*)(dst + i) = u;
  }
}

// ---------------- setup: proj cvt+pad(320), kmax init, ksuma zero ----------------
__global__ void setup_kernel(const float* __restrict__ proj,
                             unsigned short* __restrict__ projp,
                             float* __restrict__ kmax,
                             float* __restrict__ ksuma) {
  const int i = blockIdx.x * 256 + threadIdx.x;
  const int stride = gridDim.x * 256;
  for (int j = i; j < MP3_ * DH_; j += stride)
    projp[j] = (j < M_ * DH_) ? f2bf(proj[j]) : (unsigned short)0;
  for (int j = i; j < BH_; j += stride) kmax[j] = -3e38f;
  for (int j = i; j < BH_ * MP3_; j += stride) ksuma[j] = 0.f;
}

// ---------------- QKV projection: 128x128 LDS-staged MFMA GEMM ----------------
__global__ __launch_bounds__(256) void qkv_mfma(
    const unsigned short* __restrict__ x, const unsigned short* __restrict__ Wq,
    const unsigned short* __restrict__ Wk, const unsigned short* __restrict__ Wv,
    unsigned short* __restrict__ Q, unsigned short* __restrict__ K,
    unsigned short* __restrict__ VT) {
  __shared__ unsigned short As[128 * 64];
  __shared__ unsigned short Bs[128 * 64];
  const int z = blockIdx.z;
  const unsigned short* W = (z == 0) ? Wq : (z == 1) ? Wk : Wv;
  const int t0 = blockIdx.x * 128, e0 = blockIdx.y * 128;
  const int tid = threadIdx.x;
  const int wv = tid >> 6, lane = tid & 63;
  const int r = lane & 15, q = lane >> 4;
  const int wr = (wv >> 1) * 64, wc = (wv & 1) * 64;
  f32x4 acc[4][4];
#pragma unroll
  for (int i = 0; i < 4; ++i)
#pragma unroll
    for (int j = 0; j < 4; ++j) acc[i][j] = (f32x4){0.f, 0.f, 0.f, 0.f};
  const int srow = tid >> 3, scol = (tid & 7) * 8;
  for (int k0 = 0; k0 < DIM_; k0 += 64) {
#pragma unroll
    for (int j = 0; j < 4; ++j) {
      const int rr = srow + j * 32;
      *(uint4*)&As[rr * 64 + scol] = *(const uint4*)&x[(size_t)(t0 + rr) * DIM_ + k0 + scol];
      *(uint4*)&Bs[rr * 64 + scol] = *(const uint4*)&W[(size_t)(e0 + rr) * DIM_ + k0 + scol];
    }
    __syncthreads();
#pragma unroll
    for (int kc = 0; kc < 2; ++kc) {
      bf16x8 af[4], bfr[4];
#pragma unroll
      for (int rt = 0; rt < 4; ++rt)
        af[rt] = *(const bf16x8*)&As[(wr + rt * 16 + r) * 64 + kc * 32 + q * 8];
#pragma unroll
      for (int ct = 0; ct < 4; ++ct)
        bfr[ct] = *(const bf16x8*)&Bs[(wc + ct * 16 + r) * 64 + kc * 32 + q * 8];
#pragma unroll
      for (int rt = 0; rt < 4; ++rt)
#pragma unroll
        for (int ct = 0; ct < 4; ++ct)
          acc[rt][ct] = MFMA16(af[rt], bfr[ct], acc[rt][ct]);
    }
    __syncthreads();
  }
  if (z < 2) {
    unsigned short* dst = (z == 0) ? Q : K;
#pragma unroll
    for (int rt = 0; rt < 4; ++rt) {
#pragma unroll
      for (int ct = 0; ct < 4; ++ct) {
        const int e = e0 + wc + ct * 16 + r;
#pragma unroll
        for (int i = 0; i < 4; ++i) {
          const int t = t0 + wr + rt * 16 + q * 4 + i;
          dst[(size_t)t * DIM_ + e] = f2bf(acc[rt][ct][i]);
        }
      }
    }
  } else {
#pragma unroll
    for (int rt = 0; rt < 4; ++rt) {
      const int t = t0 + wr + rt * 16 + q * 4;
      const int b_ = t >> 12, n = t & (N_ - 1);
#pragma unroll
      for (int ct = 0; ct < 4; ++ct) {
        const int e = e0 + wc + ct * 16 + r;
        const int h = e >> 6, dh = e & 63;
        ushort4 pk;
        pk.x = f2bf(acc[rt][ct][0]); pk.y = f2bf(acc[rt][ct][1]);
        pk.z = f2bf(acc[rt][ct][2]); pk.w = f2bf(acc[rt][ct][3]);
        *(ushort4*)&VT[((size_t)((b_ * H_ + h) * DH_ + dh)) * N_ + n] = pk;
      }
    }
  }
}

// ---------------- diag: DIAGC * sum(t*t) per (bh, n), stored bf16 ----------------
__global__ void diag_kernel(const unsigned short* __restrict__ Q,
                            const unsigned short* __restrict__ K,
                            unsigned short* __restrict__ dq, unsigned short* __restrict__ dk) {
  const int i = blockIdx.x * 256 + threadIdx.x;
  const int bh = i >> 12, n = i & (N_ - 1);
  const int b_ = bh >> 3, h = bh & 7;
  const unsigned short* src = ((blockIdx.y == 0) ? Q : K) + (size_t)(b_ * N_ + n) * DIM_ + h * DH_;
  float s = 0.f;
#pragma unroll
  for (int c = 0; c < 16; ++c) {
    const ushort4 u = ((const ushort4*)src)[c];
    const float a = bfu(u.x), b2 = bfu(u.y), cc = bfu(u.z), d = bfu(u.w);
    s += a * a + b2 * b2 + cc * cc + d * d;
  }
  ((blockIdx.y == 0) ? dq : dk)[i] = f2bf(s * DIAGC);
}

// ---------------- kmax (MFMA): 2 n-strips per wave, 68 MFMAs/wave ----------------
__global__ __launch_bounds__(256) void kmax_mfma(
    const unsigned short* __restrict__ K, const unsigned short* __restrict__ projp,
    float* __restrict__ kmax) {
  const int bh = blockIdx.x, n0 = blockIdx.y * 128;
  const int wv = threadIdx.x >> 6, lane = threadIdx.x & 63;
  const int r = lane & 15, q = lane >> 4;
  const int b_ = bh >> 3, h = bh & 7;
  bf16x8 kb[2][2];
#pragma unroll
  for (int nt = 0; nt < 2; ++nt) {
    const int n = n0 + wv * 32 + nt * 16 + r;
    const unsigned short* krow = K + (size_t)(b_ * N_ + n) * DIM_ + h * DH_;
    kb[nt][0] = *(const bf16x8*)(krow + q * 8);
    kb[nt][1] = *(const bf16x8*)(krow + 32 + q * 8);
  }
  float runmax = -3e38f;
  for (int mt = 0; mt < 17; ++mt) {
    const unsigned short* prow = projp + (size_t)(mt * 16 + r) * DH_;
    const bf16x8 a0 = *(const bf16x8*)(prow + q * 8);
    const bf16x8 a1 = *(const bf16x8*)(prow + 32 + q * 8);
#pragma unroll
    for (int nt = 0; nt < 2; ++nt) {
      f32x4 acc = (f32x4){0.f, 0.f, 0.f, 0.f};
      acc = MFMA16(a0, kb[nt][0], acc);
      acc = MFMA16(a1, kb[nt][1], acc);
#pragma unroll
      for (int i = 0; i < 4; ++i) {
        const int m = mt * 16 + q * 4 + i;
        if (m < M_) runmax = fmaxf(runmax, acc[i]);
      }
    }
  }
  for (int s2 = 1; s2 < 64; s2 <<= 1) runmax = fmaxf(runmax, __shfl_xor(runmax, s2, 64));
  __shared__ float wm[4];
  if (lane == 0) wm[wv] = runmax;
  __syncthreads();
  if (threadIdx.x == 0) {
    const float m = fmaxf(fmaxf(wm[0], wm[1]), fmaxf(wm[2], wm[3])) * NORMC;
    atomicMaxF(&kmax[bh], m);
  }
}

// ---------------- fused: td -> exp -> kp; ctx += kp x VT; ksum ----------------
__global__ __launch_bounds__(256) void ctxfused_mfma(
    const unsigned short* __restrict__ K, const unsigned short* __restrict__ VT,
    const unsigned short* __restrict__ projp, const unsigned short* __restrict__ diag_k,
    const float* __restrict__ kmaxv, float* __restrict__ ksuma,
    float* __restrict__ slab) {
  __shared__ unsigned short kll[64][72];
  __shared__ unsigned short vtl[64][72];
  __shared__ unsigned short kpl[64][72];
  __shared__ float dgl[64];
  const int bh = blockIdx.x, m0 = blockIdx.y * 64, zi = blockIdx.z;
  const int nbase = zi * 512;
  const int tid = threadIdx.x;
  const int wv = tid >> 6, lane = tid & 63;
  const int r = lane & 15, q = lane >> 4;
  const int b_ = bh >> 3, h = bh & 7;
  const float km = kmaxv[bh];
  const unsigned short* prow = projp + (size_t)(m0 + wv * 16 + r) * DH_;
  const bf16x8 p0 = *(const bf16x8*)(prow + q * 8);
  const bf16x8 p1 = *(const bf16x8*)(prow + 32 + q * 8);
  const unsigned short* kbase = K + (size_t)(b_ * N_) * DIM_ + h * DH_;
  const unsigned short* vbase = VT + (size_t)bh * DH_ * N_;
  f32x4 cacc[4];
#pragma unroll
  for (int i = 0; i < 4; ++i) cacc[i] = (f32x4){0.f, 0.f, 0.f, 0.f};
  float ksa[4] = {0.f, 0.f, 0.f, 0.f};
  for (int nc = 0; nc < 8; ++nc) {
    const int n0c = nbase + nc * 64;
#pragma unroll
    for (int j = 0; j < 4; ++j) {
      const int idx = tid + j * 256;
      const int rr = idx >> 4, c4 = (idx & 15) << 2;
      *(ushort4*)&kll[rr][c4] = *(const ushort4*)&kbase[(size_t)(n0c + rr) * DIM_ + c4];
      *(ushort4*)&vtl[rr][c4] = *(const ushort4*)&vbase[(size_t)rr * N_ + n0c + c4];
    }
    if (tid < 16) {
      const ushort4 du = *(const ushort4*)&diag_k[bh * N_ + n0c + tid * 4];
      dgl[tid * 4 + 0] = bfu(du.x); dgl[tid * 4 + 1] = bfu(du.y);
      dgl[tid * 4 + 2] = bfu(du.z); dgl[tid * 4 + 3] = bfu(du.w);
    }
    __syncthreads();
#pragma unroll
    for (int nt = 0; nt < 4; ++nt) {
      const bf16x8 kb0 = *(const bf16x8*)&kll[nt * 16 + r][q * 8];
      const bf16x8 kb1 = *(const bf16x8*)&kll[nt * 16 + r][32 + q * 8];
      f32x4 acc = (f32x4){0.f, 0.f, 0.f, 0.f};
      acc = MFMA16(p0, kb0, acc);
      acc = MFMA16(p1, kb1, acc);
      const float dgk = dgl[nt * 16 + r];
#pragma unroll
      for (int i = 0; i < 4; ++i) {
        const int m = m0 + wv * 16 + q * 4 + i;
        float kp = 0.f;
        if (m < M_) {
          const float arg = fminf(NORMC * acc[i] - dgk - km, 0.f);
          kp = RATIOC * (__expf(arg) + EPSK);
        }
        kpl[wv * 16 + q * 4 + i][nt * 16 + r] = f2bf(kp);
        ksa[i] += kp;
      }
    }
    __syncthreads();
    {
      const bf16x8 a0 = *(const bf16x8*)&kpl[wv * 16 + r][q * 8];
      const bf16x8 a1 = *(const bf16x8*)&kpl[wv * 16 + r][32 + q * 8];
#pragma unroll
      for (int ct = 0; ct < 4; ++ct) {
        const bf16x8 b0 = *(const bf16x8*)&vtl[ct * 16 + r][q * 8];
        const bf16x8 b1 = *(const bf16x8*)&vtl[ct * 16 + r][32 + q * 8];
        cacc[ct] = MFMA16(a0, b0, cacc[ct]);
        cacc[ct] = MFMA16(a1, b1, cacc[ct]);
      }
    }
    __syncthreads();
  }
#pragma unroll
  for (int i = 0; i < 4; ++i)
    for (int s2 = 1; s2 < 16; s2 <<= 1) ksa[i] += __shfl_xor(ksa[i], s2, 64);
  if (r == 0) {
#pragma unroll
    for (int i = 0; i < 4; ++i)
      atomicAdd(&ksuma[bh * MP3_ + m0 + wv * 16 + q * 4 + i], ksa[i]);
  }
  float* sl = slab + (size_t)(bh * NZ_ + zi) * SLABM_ * DH_;
#pragma unroll
  for (int ct = 0; ct < 4; ++ct) {
#pragma unroll
    for (int i = 0; i < 4; ++i) {
      const int m = m0 + wv * 16 + q * 4 + i;
      if (m < SLABM_) sl[(size_t)m * DH_ + ct * 16 + r] = cacc[ct][i];
    }
  }
}

// ---------------- pack: reduce 8 z-slabs [m][d] fp32 -> transpose -> ctxT [d][288] bf16 ----
__global__ __launch_bounds__(256) void pack_kernel(const float* __restrict__ slab,
                                                   unsigned short* __restrict__ ctxT) {
  __shared__ float t[64][65];
  const int bh = blockIdx.x, m0 = blockIdx.y * 64;
  const int tid = threadIdx.x;
  const int mr = tid >> 4, d4 = (tid & 15) * 4;
#pragma unroll
  for (int pass = 0; pass < 4; ++pass) {
    const int ml = pass * 16 + mr;
    const int m = m0 + ml;
    float4 s = {0.f, 0.f, 0.f, 0.f};
    if (m < SLABM_) {
#pragma unroll
      for (int z = 0; z < NZ_; ++z) {
        const float4 v =
            *(const float4*)&slab[((size_t)(bh * NZ_ + z) * SLABM_ + m) * DH_ + d4];
        s.x += v.x; s.y += v.y; s.z += v.z; s.w += v.w;
      }
    }
    t[ml][d4 + 0] = s.x; t[ml][d4 + 1] = s.y; t[ml][d4 + 2] = s.z; t[ml][d4 + 3] = s.w;
  }
  __syncthreads();
  const int mc = tid & 63, dbase = tid >> 6;
  const int mo = m0 + mc;
  if (mo < MP2_) {
#pragma unroll
    for (int j = 0; j < 16; ++j) {
      const int d = dbase + j * 4;
      ctxT[((size_t)bh * DH_ + d) * MP2_ + mo] = f2bf(t[mc][d]);
    }
  }
}

// ---------------- fused QP + out GEMM: swapped-operand, LDS-free, barrier-free ----------------
// Phase A computes mfma(proj, Q) so each lane owns td[m = mt*16+q*4+i][n = n0+wv*16+r]:
// rmax / diag / denom are per-lane scalars. qp packed to bf16 pairs (v_cvt_pk_bf16_f32).
// Phase C A-fragments (8 consecutive m per lane) assembled via wave shuffles from the
// two fixed holder lanes ((q&1)*2{,+1})*16 + r, two offer-rounds selected by q>>1.
__global__ __launch_bounds__(256) void qpout_mfma(
    const unsigned short* __restrict__ Qb, const unsigned short* __restrict__ projp,
    const unsigned short* __restrict__ diag_q, const float* __restrict__ ksuma,
    const unsigned short* __restrict__ ctxT, unsigned short* __restrict__ attn) {
  const int bh = blockIdx.x, n0 = blockIdx.y * 64;
  const int wv = threadIdx.x >> 6, lane = threadIdx.x & 63;
  const int r = lane & 15, q = lane >> 4;
  const int b_ = bh >> 3, h = bh & 7;
  // B-fragment: Q row n = n0 + wv*16 + r
  const unsigned short* qrow = Qb + (size_t)(b_ * N_ + n0 + wv * 16 + r) * DIM_ + h * DH_;
  const bf16x8 qb0 = *(const bf16x8*)(qrow + q * 8);
  const bf16x8 qb1 = *(const bf16x8*)(qrow + 32 + q * 8);
  // Phase A (swapped): tdv[mt][i] = raw td[m = mt*16+q*4+i][n]
  float tdv[17][4];
#pragma unroll
  for (int mt = 0; mt < 17; ++mt) {
    const unsigned short* prow = projp + (size_t)(mt * 16 + r) * DH_;
    const bf16x8 p0 = *(const bf16x8*)(prow + q * 8);
    const bf16x8 p1 = *(const bf16x8*)(prow + 32 + q * 8);
    f32x4 acc = (f32x4){0.f, 0.f, 0.f, 0.f};
    acc = MFMA16(p0, qb0, acc);
    acc = MFMA16(p1, qb1, acc);
#pragma unroll
    for (int i = 0; i < 4; ++i) tdv[mt][i] = acc[i];
  }
  // per-n max over valid m (m < 266); mt=16 holds m=256..271, valid iff q*4+i < 10
  float rm = -3e38f;
#pragma unroll
  for (int mt = 0; mt < 16; ++mt)
#pragma unroll
    for (int i = 0; i < 4; ++i) rm = fmaxf(rm, tdv[mt][i]);
#pragma unroll
  for (int i = 0; i < 4; ++i)
    rm = (q * 4 + i < 10) ? fmaxf(rm, tdv[16][i]) : rm;
  rm = fmaxf(rm, __shfl_xor(rm, 16, 64));
  rm = fmaxf(rm, __shfl_xor(rm, 32, 64));
  const float dg = bfu(diag_q[bh * N_ + n0 + wv * 16 + r]);
  const float Cl = LOG2R - dg * LOG2E - rm * KA;
  // exp + pack + denominator partial (rounded qp for consistency; ksums[m>=266]=0)
  unsigned int pk[18][2];
  pk[17][0] = 0u; pk[17][1] = 0u;
  float part = 0.f;
#pragma unroll
  for (int mt = 0; mt < 17; ++mt) {
    const f32x4 kl = *(const f32x4*)&ksuma[bh * MP3_ + mt * 16 + q * 4];
#pragma unroll
    for (int p = 0; p < 2; ++p) {
      const float s0 = fminf(tdv[mt][2 * p] * KA + Cl, LOG2R);
      const float s1 = fminf(tdv[mt][2 * p + 1] * KA + Cl, LOG2R);
      const float e0 = exp2f(s0) + REPS;
      const float e1 = exp2f(s1) + REPS;
      unsigned int pkk;
      asm("v_cvt_pk_bf16_f32 %0, %1, %2" : "=v"(pkk) : "v"(e0), "v"(e1));
      pk[mt][p] = pkk;
      union { unsigned int u; float f; } lo, hi;
      lo.u = pkk << 16; hi.u = pkk & 0xffff0000u;
      part += lo.f * kl[2 * p] + hi.f * kl[2 * p + 1];
    }
  }
  part += __shfl_xor(part, 16, 64);
  part += __shfl_xor(part, 32, 64);
  const float dinv = 1.f / fmaxf(part, 1e-30f);
  // Phase C: out = qp . ctxT (K = 288), A-fragments via shuffles
  const int srcA = ((q & 1) << 5) + r;   // holder lane q_s = (q&1)*2
  const int srcB = srcA + 16;            // holder lane q_s = (q&1)*2+1
  f32x4 oacc[4];
#pragma unroll
  for (int i = 0; i < 4; ++i) oacc[i] = (f32x4){0.f, 0.f, 0.f, 0.f};
  const unsigned short* cbase = ctxT + (size_t)bh * DH_ * MP2_;
  const bool hi2 = (q >> 1) != 0;
#pragma unroll
  for (int kc = 0; kc < 9; ++kc) {
    const unsigned int vA0 = __shfl((int)pk[2 * kc][0], srcA, 64);
    const unsigned int vA1 = __shfl((int)pk[2 * kc][1], srcA, 64);
    const unsigned int vB0 = __shfl((int)pk[2 * kc][0], srcB, 64);
    const unsigned int vB1 = __shfl((int)pk[2 * kc][1], srcB, 64);
    const unsigned int wA0 = __shfl((int)pk[2 * kc + 1][0], srcA, 64);
    const unsigned int wA1 = __shfl((int)pk[2 * kc + 1][1], srcA, 64);
    const unsigned int wB0 = __shfl((int)pk[2 * kc + 1][0], srcB, 64);
    const unsigned int wB1 = __shfl((int)pk[2 * kc + 1][1], srcB, 64);
    union { unsigned int u[4]; bf16x8 v; } af;
    af.u[0] = hi2 ? wA0 : vA0;
    af.u[1] = hi2 ? wA1 : vA1;
    af.u[2] = hi2 ? wB0 : vB0;
    af.u[3] = hi2 ? wB1 : vB1;
#pragma unroll
    for (int dt = 0; dt < 4; ++dt) {
      const bf16x8 bfr = *(const bf16x8*)&cbase[(size_t)(dt * 16 + r) * MP2_ + kc * 32 + q * 8];
      oacc[dt] = MFMA16(af.v, bfr, oacc[dt]);
    }
  }
  // dinv lives at lane r = n-local; rows n-local = q*4+i need it -> intra-group shfl
  float dv[4];
#pragma unroll
  for (int i = 0; i < 4; ++i)
    dv[i] = __shfl(dinv, (lane & 48) | (q * 4 + i), 64);
#pragma unroll
  for (int dt = 0; dt < 4; ++dt) {
    const int d = dt * 16 + r;
#pragma unroll
    for (int i = 0; i < 4; ++i) {
      const int nn = wv * 16 + q * 4 + i;
      attn[(size_t)(b_ * N_ + n0 + nn) * DIM_ + h * DH_ + d] = f2bf(oacc[dt][i] * dv[i]);
    }
  }
}

// ---------------- final: 128x128 LDS-staged MFMA GEMM + residual (fp32 I/O) ----------------
__global__ __launch_bounds__(256) void final_mfma(
    const unsigned short* __restrict__ attn, const unsigned short* __restrict__ Wo,
    const float* __restrict__ bo, const float* __restrict__ x,
    float* __restrict__ out) {
  __shared__ unsigned short As[128 * 64];
  __shared__ unsigned short Bs[128 * 64];
  const int t0 = blockIdx.x * 128, e0 = blockIdx.y * 128;
  const int tid = threadIdx.x;
  const int wv = tid >> 6, lane = tid & 63;
  const int r = lane & 15, q = lane >> 4;
  const int wr = (wv >> 1) * 64, wc = (wv & 1) * 64;
  f32x4 acc[4][4];
#pragma unroll
  for (int i = 0; i < 4; ++i)
#pragma unroll
    for (int j = 0; j < 4; ++j) acc[i][j] = (f32x4){0.f, 0.f, 0.f, 0.f};
  const int srow = tid >> 3, scol = (tid & 7) * 8;
  for (int k0 = 0; k0 < DIM_; k0 += 64) {
#pragma unroll
    for (int j = 0; j < 4; ++j) {
      const int rr = srow + j * 32;
      *(uint4*)&As[rr * 64 + scol] = *(const uint4*)&attn[(size_t)(t0 + rr) * DIM_ + k0 + scol];
      *(uint4*)&Bs[rr * 64 + scol] = *(const uint4*)&Wo[(size_t)(e0 + rr) * DIM_ + k0 + scol];
    }
    __syncthreads();
#pragma unroll
    for (int kc = 0; kc < 2; ++kc) {
      bf16x8 af[4], bfr[4];
#pragma unroll
      for (int rt = 0; rt < 4; ++rt)
        af[rt] = *(const bf16x8*)&As[(wr + rt * 16 + r) * 64 + kc * 32 + q * 8];
#pragma unroll
      for (int ct = 0; ct < 4; ++ct)
        bfr[ct] = *(const bf16x8*)&Bs[(wc + ct * 16 + r) * 64 + kc * 32 + q * 8];
#pragma unroll
      for (int rt = 0; rt < 4; ++rt)
#pragma unroll
        for (int ct = 0; ct < 4; ++ct)
          acc[rt][ct] = MFMA16(af[rt], bfr[ct], acc[rt][ct]);
    }
    __syncthreads();
  }
#pragma unroll
  for (int rt = 0; rt < 4; ++rt) {
#pragma unroll
    for (int ct = 0; ct < 4; ++ct) {
      const int c = e0 + wc + ct * 16 + r;
      const float bov = bo[c];
#pragma unroll
      for (int i = 0; i < 4; ++i) {
        const int t = t0 + wr + rt * 16 + q * 4 + i;
        out[(size_t)t * DIM_ + c] = acc[rt][ct][i] + bov + x[(size_t)t * DIM_ + c];
      }
    }
  }
}

extern "C" void kernel_launch(void* const* d_in, const int* in_sizes, int n_in,
                              void* d_out, int out_size, void* d_ws, size_t ws_size,
                              hipStream_t stream) {
  const float* x = (const float*)d_in[0];
  const float* Wq = (const float*)d_in[1];
  const float* Wk = (const float*)d_in[2];
  const float* Wv = (const float*)d_in[3];
  const float* Wo = (const float*)d_in[4];
  const float* bo = (const float*)d_in[5];
  const float* proj = (const float*)d_in[6];
  char* ws = (char*)d_ws;
  unsigned short* projp = (unsigned short*)(ws + PROJP_B);
  float* kmax = (float*)(ws + KMAX_B);
  float* ksuma = (float*)(ws + KSUMA_B);
  float* ctxa = (float*)(ws + CTXA_B);
  unsigned short* ctxT = (unsigned short*)(ws + CTXT_B);
  unsigned short* diag_q = (unsigned short*)(ws + DIAGQ_B);
  unsigned short* diag_k = (unsigned short*)(ws + DIAGK_B);
  unsigned short* xbf = (unsigned short*)(ws + XBF_B);
  unsigned short* wqb = (unsigned short*)(ws + WQ_B);
  unsigned short* wkb = (unsigned short*)(ws + WK_B);
  unsigned short* wvb = (unsigned short*)(ws + WV_B);
  unsigned short* wob = (unsigned short*)(ws + WO_B);
  unsigned short* Q = (unsigned short*)(ws + Q_B);
  unsigned short* K = (unsigned short*)(ws + K_B);
  unsigned short* VT = (unsigned short*)(ws + VT_B);
  unsigned short* attn = K;  // K dead after ctxfused_mfma
  float* out = (float*)d_out;

  cvt_kernel<<<1024, 256, 0, stream>>>(x, xbf, 8388608);
  cvt_kernel<<<128, 256, 0, stream>>>(Wq, wqb, 262144);
  cvt_kernel<<<128, 256, 0, stream>>>(Wk, wkb, 262144);
  cvt_kernel<<<128, 256, 0, stream>>>(Wv, wvb, 262144);
  cvt_kernel<<<128, 256, 0, stream>>>(Wo, wob, 262144);
  setup_kernel<<<80, 256, 0, stream>>>(proj, projp, kmax, ksuma);
  qkv_mfma<<<dim3(NT_ / 128, DIM_ / 128, 3), 256, 0, stream>>>(xbf, wqb, wkb, wvb, Q, K, VT);
  diag_kernel<<<dim3(512, 2), 256, 0, stream>>>(Q, K, diag_q, diag_k);
  kmax_mfma<<<dim3(BH_, 32), 256, 0, stream>>>(K, projp, kmax);
  ctxfused_mfma<<<dim3(BH_, 5, NZ_), 256, 0, stream>>>(K, VT, projp, diag_k, kmax, ksuma, ctxa);
  pack_kernel<<<dim3(BH_, 5), 256, 0, stream>>>(ctxa, ctxT);
  qpout_mfma<<<dim3(BH_, 64), 256, 0, stream>>>(Q, projp, diag_q, ksuma, ctxT, attn);
  final_mfma<<<dim3(NT_ / 128, DIM_ / 128), 256, 0, stream>>>(attn, wob, bo, x, out);
}